// Round 4
// baseline (3416.455 us; speedup 1.0000x reference)
//
#include <hip/hip_runtime.h>

#define N_POINTS    100000
#define N_KEYPOINTS 16384
#define N_PAIRS     524288
#define D_OUT       300
#define TP          64     // pairs per LDS tile
#define PB          16     // phase-2 pair block (acc regs = 2*PB)
#define TR          32     // output-MLP row tile

// ---------------------------------------------------------------------------
// CSR build: count pairs per keypoint, exclusive scan, fill sorted pair list.
// ---------------------------------------------------------------------------
__global__ __launch_bounds__(256) void k_count(const int* __restrict__ si_set,
                                               int* __restrict__ cnt) {
    const int s = blockIdx.x * 256 + threadIdx.x;
    if (s < N_PAIRS) atomicAdd(&cnt[si_set[s]], 1);
}

__global__ __launch_bounds__(256) void k_scan(const int* __restrict__ cnt,
                                              int* __restrict__ off,
                                              int* __restrict__ cursor) {
    __shared__ int part[256];
    const int t = threadIdx.x;
    const int base = t * 64;   // 16384 / 256
    int s = 0;
    for (int k = 0; k < 64; ++k) s += cnt[base + k];
    part[t] = s;
    __syncthreads();
    for (int d = 1; d < 256; d <<= 1) {
        int add = (t >= d) ? part[t - d] : 0;
        __syncthreads();
        part[t] += add;
        __syncthreads();
    }
    int run = part[t] - s;
    for (int k = 0; k < 64; ++k) {
        off[base + k] = run;
        cursor[base + k] = run;
        run += cnt[base + k];
    }
    if (t == 255) off[N_KEYPOINTS] = run;
}

__global__ __launch_bounds__(256) void k_fill(const int* __restrict__ si_set,
                                              int* __restrict__ cursor,
                                              int* __restrict__ pairlist) {
    const int s = blockIdx.x * 256 + threadIdx.x;
    if (s < N_PAIRS) {
        const int st = si_set[s];
        const int pos = atomicAdd(&cursor[st], 1);
        pairlist[pos] = s;
    }
}

// ---------------------------------------------------------------------------
// Fused point MLP + segmented max. Block = 2 keypoints, 320 threads.
// Phase 1: 4 threads/pair compute layers 1-3 -> x3T tile in LDS (transposed).
// Phase 2: 300 threads (150 per keypoint, 2 cols each) do layer 4 + max with
// PB x 2 register blocking; no atomics, no global X3.
// __launch_bounds__(320, 1): allow a large VGPR budget -- round 3 showed the
// default allocation (56 VGPRs) spilled both phases to scratch (10x cost).
// ---------------------------------------------------------------------------
__global__ __launch_bounds__(320, 1) void fused_point(
    const float* __restrict__ features, const float* __restrict__ coords,
    const int* __restrict__ keypoints, const int* __restrict__ set_indices,
    const int* __restrict__ pairlist, const int* __restrict__ off,
    const float* __restrict__ pw1, const float* __restrict__ pb1,
    const float* __restrict__ pw2, const float* __restrict__ pb2,
    const float* __restrict__ pw3, const float* __restrict__ pb3,
    const float* __restrict__ pw4, const float* __restrict__ pb4,
    float* __restrict__ agg)
{
    __shared__ float x3T[128][TP];   // 32 KB, transposed: [col][pair]

    const int t  = threadIdx.x;
    const int gA = blockIdx.x * 2;
    const int p  = t & 63;           // pair slot within tile
    const int q  = t >> 6;           // 0..4 (q==4 idle in phase 1)

    const int base   = off[gA];
    const int endAll = off[gA + 2];
    const int nt     = (endAll - base + TP - 1) >> 6;

    const bool p2act = (t < 300);
    const int  cc    = (t < 150) ? t : t - 150;   // column base (cc, cc+150)
    const int  gsel  = (t < 150) ? 0 : 1;
    const int  gs    = off[gA + gsel];
    const int  ge    = off[gA + gsel + 1];
    float vmax0 = -INFINITY, vmax1 = -INFINITY;

    for (int it = 0; it < nt; ++it) {
        const int t0 = base + (it << 6);
        int np = endAll - t0; if (np > TP) np = TP;

        // ---------------- Phase 1: layers 1-3 into LDS ----------------
        if (q < 4 && p < np) {
            const int pair = pairlist[t0 + p];
            const int pt = set_indices[pair];
            const int st = set_indices[N_PAIRS + pair];
            const int kp = keypoints[st];

            float x0[4];
            x0[0] = features[pt];
            x0[1] = coords[pt * 3 + 0] - coords[kp * 3 + 0];
            x0[2] = coords[pt * 3 + 1] - coords[kp * 3 + 1];
            x0[3] = coords[pt * 3 + 2] - coords[kp * 3 + 2];

            float x1[32];
#pragma unroll
            for (int j = 0; j < 32; ++j) {
                float a = pb1[j];
#pragma unroll
                for (int k = 0; k < 4; ++k) a = fmaf(x0[k], pw1[k * 32 + j], a);
                x1[j] = fmaxf(a, 0.f);
            }

            float x2[64];
#pragma unroll
            for (int j = 0; j < 64; ++j) {
                float a = pb2[j];
#pragma unroll
                for (int k = 0; k < 32; ++k) a = fmaf(x1[k], pw2[k * 64 + j], a);
                x2[j] = fmaxf(a, 0.f);
            }

            // layer-3 quarter: cols [32q, 32q+32)
            for (int i = 0; i < 4; ++i) {
                const int jb = (q << 5) + (i << 3);
                float acc[8];
#pragma unroll
                for (int jj = 0; jj < 8; ++jj) acc[jj] = pb3[jb + jj];
#pragma unroll
                for (int k = 0; k < 64; ++k) {
                    const float xk = x2[k];
#pragma unroll
                    for (int jj = 0; jj < 8; ++jj)
                        acc[jj] = fmaf(xk, pw3[k * 128 + jb + jj], acc[jj]);
                }
#pragma unroll
                for (int jj = 0; jj < 8; ++jj)
                    x3T[jb + jj][p] = fmaxf(acc[jj], 0.f);
            }
        }
        __syncthreads();

        // ---------------- Phase 2: layer 4 + running max ----------------
        if (p2act) {
            int as = gs - t0; if (as < 0) as = 0;
            int ae = ge - t0; if (ae > np) ae = np;
            for (int jb = (as & ~(PB - 1)); jb < ae; jb += PB) {
                float acc0[PB], acc1[PB];
#pragma unroll
                for (int i = 0; i < PB; ++i) { acc0[i] = 0.f; acc1[i] = 0.f; }
                for (int k = 0; k < 128; ++k) {
                    const float wa = pw4[k * D_OUT + cc];
                    const float wb = pw4[k * D_OUT + cc + 150];
#pragma unroll
                    for (int u = 0; u < PB / 4; ++u) {
                        const float4 xv = *(const float4*)&x3T[k][jb + 4 * u];
                        acc0[4*u+0] = fmaf(xv.x, wa, acc0[4*u+0]);
                        acc0[4*u+1] = fmaf(xv.y, wa, acc0[4*u+1]);
                        acc0[4*u+2] = fmaf(xv.z, wa, acc0[4*u+2]);
                        acc0[4*u+3] = fmaf(xv.w, wa, acc0[4*u+3]);
                        acc1[4*u+0] = fmaf(xv.x, wb, acc1[4*u+0]);
                        acc1[4*u+1] = fmaf(xv.y, wb, acc1[4*u+1]);
                        acc1[4*u+2] = fmaf(xv.z, wb, acc1[4*u+2]);
                        acc1[4*u+3] = fmaf(xv.w, wb, acc1[4*u+3]);
                    }
                }
#pragma unroll
                for (int i = 0; i < PB; ++i) {
                    const int s = jb + i;
                    if (s >= as && s < ae) {
                        vmax0 = fmaxf(vmax0, acc0[i]);
                        vmax1 = fmaxf(vmax1, acc1[i]);
                    }
                }
            }
        }
        __syncthreads();
    }

    if (p2act) {
        const int g = gA + gsel;
        // empty segment: vmax=-inf -> result 0 (matches max(segment_max,0))
        agg[(size_t)g * D_OUT + cc]       = fmaxf(vmax0 + pb4[cc], 0.f);
        agg[(size_t)g * D_OUT + cc + 150] = fmaxf(vmax1 + pb4[cc + 150], 0.f);
    }
}

// ---------------------------------------------------------------------------
// Output MLP (unchanged; in-place safe: block reads its 32 rows before write).
// ---------------------------------------------------------------------------
__global__ __launch_bounds__(320, 2) void out_mlp(
    const float* __restrict__ agg,
    const float* __restrict__ ow1, const float* __restrict__ ob1,
    const float* __restrict__ ow2, const float* __restrict__ ob2,
    float* __restrict__ y)
{
    __shared__ float A[TR * D_OUT];
    __shared__ float H[TR * D_OUT];
    const int t = threadIdx.x;
    const long rb = (long)blockIdx.x * TR;

    for (int l = t; l < TR * D_OUT; l += 320) A[l] = agg[rb * D_OUT + l];
    __syncthreads();

    if (t < D_OUT) {
        float acc[TR];
#pragma unroll
        for (int r = 0; r < TR; ++r) acc[r] = ob1[t];
        for (int k = 0; k < D_OUT; k += 4) {
            const float w0 = ow1[(k + 0) * D_OUT + t];
            const float w1 = ow1[(k + 1) * D_OUT + t];
            const float w2 = ow1[(k + 2) * D_OUT + t];
            const float w3 = ow1[(k + 3) * D_OUT + t];
#pragma unroll
            for (int r = 0; r < TR; ++r) {
                const float4 a4 = *reinterpret_cast<const float4*>(&A[r * D_OUT + k]);
                acc[r] = fmaf(a4.x, w0, acc[r]);
                acc[r] = fmaf(a4.y, w1, acc[r]);
                acc[r] = fmaf(a4.z, w2, acc[r]);
                acc[r] = fmaf(a4.w, w3, acc[r]);
            }
        }
#pragma unroll
        for (int r = 0; r < TR; ++r) H[r * D_OUT + t] = fmaxf(acc[r], 0.f);
    }
    __syncthreads();

    if (t < D_OUT) {
        float acc[TR];
#pragma unroll
        for (int r = 0; r < TR; ++r) acc[r] = ob2[t];
        for (int k = 0; k < D_OUT; k += 4) {
            const float w0 = ow2[(k + 0) * D_OUT + t];
            const float w1 = ow2[(k + 1) * D_OUT + t];
            const float w2 = ow2[(k + 2) * D_OUT + t];
            const float w3 = ow2[(k + 3) * D_OUT + t];
#pragma unroll
            for (int r = 0; r < TR; ++r) {
                const float4 h4 = *reinterpret_cast<const float4*>(&H[r * D_OUT + k]);
                acc[r] = fmaf(h4.x, w0, acc[r]);
                acc[r] = fmaf(h4.y, w1, acc[r]);
                acc[r] = fmaf(h4.z, w2, acc[r]);
                acc[r] = fmaf(h4.w, w3, acc[r]);
            }
        }
#pragma unroll
        for (int r = 0; r < TR; ++r) y[(rb + r) * D_OUT + t] = fmaxf(acc[r], 0.f);
    }
}

extern "C" void kernel_launch(void* const* d_in, const int* in_sizes, int n_in,
                              void* d_out, int out_size, void* d_ws, size_t ws_size,
                              hipStream_t stream) {
    const float* features    = (const float*)d_in[0];
    const float* coords      = (const float*)d_in[1];
    const int*   keypoints   = (const int*)d_in[2];
    const int*   set_indices = (const int*)d_in[3];
    const float* pw1 = (const float*)d_in[4];
    const float* pb1 = (const float*)d_in[5];
    const float* pw2 = (const float*)d_in[6];
    const float* pb2 = (const float*)d_in[7];
    const float* pw3 = (const float*)d_in[8];
    const float* pb3 = (const float*)d_in[9];
    const float* pw4 = (const float*)d_in[10];
    const float* pb4 = (const float*)d_in[11];
    const float* ow1 = (const float*)d_in[12];
    const float* ob1 = (const float*)d_in[13];
    const float* ow2 = (const float*)d_in[14];
    const float* ob2 = (const float*)d_in[15];

    const int* si_set = set_indices + N_PAIRS;

    // ws layout: CSR only (~2.2 MB)
    char* w = (char*)d_ws;
    int* cnt      = (int*)w;  w += 65536;
    int* off      = (int*)w;  w += 65792;   // 16385 ints, padded
    int* cursor   = (int*)w;  w += 65536;
    int* pairlist = (int*)w;

    float* agg = (float*)d_out;   // out_mlp runs in-place (read-before-write)
    float* y   = (float*)d_out;

    hipMemsetAsync(cnt, 0, 65536, stream);
    k_count<<<N_PAIRS / 256, 256, 0, stream>>>(si_set, cnt);
    k_scan<<<1, 256, 0, stream>>>(cnt, off, cursor);
    k_fill<<<N_PAIRS / 256, 256, 0, stream>>>(si_set, cursor, pairlist);

    fused_point<<<N_KEYPOINTS / 2, 320, 0, stream>>>(
        features, coords, keypoints, set_indices, pairlist, off,
        pw1, pb1, pw2, pb2, pw3, pb3, pw4, pb4, agg);

    out_mlp<<<N_KEYPOINTS / TR, 320, 0, stream>>>(agg, ow1, ob1, ow2, ob2, y);
}

// Round 5
// 2098.985 us; speedup vs baseline: 1.6277x; 1.6277x over previous
//
#include <hip/hip_runtime.h>

#define N_POINTS    100000
#define N_KEYPOINTS 16384
#define N_PAIRS     524288
#define D_OUT       300
#define TP          64     // pairs per LDS tile
#define PB          16     // phase-2 pair block (acc regs = 2*PB)
#define TR          32     // output-MLP row tile

// ---------------------------------------------------------------------------
// CSR build: count pairs per keypoint, exclusive scan, fill sorted pair list.
// ---------------------------------------------------------------------------
__global__ __launch_bounds__(256) void k_count(const int* __restrict__ si_set,
                                               int* __restrict__ cnt) {
    const int s = blockIdx.x * 256 + threadIdx.x;
    if (s < N_PAIRS) atomicAdd(&cnt[si_set[s]], 1);
}

__global__ __launch_bounds__(256) void k_scan(const int* __restrict__ cnt,
                                              int* __restrict__ off,
                                              int* __restrict__ cursor) {
    __shared__ int part[256];
    const int t = threadIdx.x;
    const int base = t * 64;   // 16384 / 256
    int s = 0;
    for (int k = 0; k < 64; ++k) s += cnt[base + k];
    part[t] = s;
    __syncthreads();
    for (int d = 1; d < 256; d <<= 1) {
        int add = (t >= d) ? part[t - d] : 0;
        __syncthreads();
        part[t] += add;
        __syncthreads();
    }
    int run = part[t] - s;
    for (int k = 0; k < 64; ++k) {
        off[base + k] = run;
        cursor[base + k] = run;
        run += cnt[base + k];
    }
    if (t == 255) off[N_KEYPOINTS] = run;
}

__global__ __launch_bounds__(256) void k_fill(const int* __restrict__ si_set,
                                              int* __restrict__ cursor,
                                              int* __restrict__ pairlist) {
    const int s = blockIdx.x * 256 + threadIdx.x;
    if (s < N_PAIRS) {
        const int st = si_set[s];
        const int pos = atomicAdd(&cursor[st], 1);
        pairlist[pos] = s;
    }
}

// ---------------------------------------------------------------------------
// Fused point MLP + segmented max. Block = 2 keypoints, 320 threads.
// Phase 1 is LAYER-BY-LAYER through LDS so no thread ever holds a whole
// activation vector (rounds 3-4: x1[32]+x2[64] live => compiler spilled to
// scratch, 10x slowdown). Max live regs anywhere ~= 60.
//   1a: 64 threads (1/pair): gather + layer 1 -> x1T[32][TP]
//   1b: 256 threads (pair=lane, 16-col quarter/wave): layer 2 -> x2T[64][TP]
//   1c: 256 threads (32-col quarter/wave): layer 3 -> x3T[128][TP]
//   2 : 300 threads (150/keypoint, 2 cols each): layer 4 + running max,
//       PB-pair register blocking, LDS reads are wave-broadcast b128.
// Weight addresses in 1b/1c are wave-uniform (readfirstlane on wave id)
// -> scalar s_load broadcasts, no per-lane VMEM.
// ---------------------------------------------------------------------------
__global__ __launch_bounds__(320, 2) void fused_point(
    const float* __restrict__ features, const float* __restrict__ coords,
    const int* __restrict__ keypoints, const int* __restrict__ set_indices,
    const int* __restrict__ pairlist, const int* __restrict__ off,
    const float* __restrict__ pw1, const float* __restrict__ pb1,
    const float* __restrict__ pw2, const float* __restrict__ pb2,
    const float* __restrict__ pw3, const float* __restrict__ pb3,
    const float* __restrict__ pw4, const float* __restrict__ pb4,
    float* __restrict__ agg)
{
    __shared__ float x1T[32][TP];    //  8 KB  [col][pair]
    __shared__ float x2T[64][TP];    // 16 KB
    __shared__ float x3T[128][TP];   // 32 KB

    const int t  = threadIdx.x;
    const int gA = blockIdx.x * 2;
    const int p  = t & 63;                                  // pair lane
    const int qq = __builtin_amdgcn_readfirstlane(t >> 6);  // wave id 0..4

    const int base   = off[gA];
    const int endAll = off[gA + 2];
    const int nt     = (endAll - base + TP - 1) >> 6;

    const bool p2act = (t < 300);
    const int  cc    = (t < 150) ? t : t - 150;   // column base (cc, cc+150)
    const int  gsel  = (t < 150) ? 0 : 1;
    const int  gs    = off[gA + gsel];
    const int  ge    = off[gA + gsel + 1];
    float vmax0 = -INFINITY, vmax1 = -INFINITY;

    for (int it = 0; it < nt; ++it) {
        const int t0 = base + (it << 6);
        int np = endAll - t0; if (np > TP) np = TP;

        // ---- 1a: gather + layer 1 (4 -> 32), one thread per pair ----
        if (t < 64 && t < np) {
            const int pair = pairlist[t0 + t];
            const int pt = set_indices[pair];
            const int st = set_indices[N_PAIRS + pair];
            const int kp = keypoints[st];

            float x0[4];
            x0[0] = features[pt];
            x0[1] = coords[pt * 3 + 0] - coords[kp * 3 + 0];
            x0[2] = coords[pt * 3 + 1] - coords[kp * 3 + 1];
            x0[3] = coords[pt * 3 + 2] - coords[kp * 3 + 2];

#pragma unroll
            for (int j = 0; j < 32; ++j) {
                float a = pb1[j];
#pragma unroll
                for (int k = 0; k < 4; ++k) a = fmaf(x0[k], pw1[k * 32 + j], a);
                x1T[j][t] = fmaxf(a, 0.f);
            }
        }
        __syncthreads();

        // ---- 1b: layer 2 (32 -> 64), 16-col quarter per wave ----
        if (qq < 4 && p < np) {
            const int jc = qq << 4;            // 0,16,32,48 (wave-uniform)
            float acc[16];
#pragma unroll
            for (int jj = 0; jj < 16; ++jj) acc[jj] = pb2[jc + jj];
            for (int k = 0; k < 32; ++k) {
                const float xk = x1T[k][p];
#pragma unroll
                for (int jj = 0; jj < 16; ++jj)
                    acc[jj] = fmaf(xk, pw2[k * 64 + jc + jj], acc[jj]);
            }
#pragma unroll
            for (int jj = 0; jj < 16; ++jj)
                x2T[jc + jj][p] = fmaxf(acc[jj], 0.f);
        }
        __syncthreads();

        // ---- 1c: layer 3 (64 -> 128), 32-col quarter per wave ----
        if (qq < 4 && p < np) {
            const int jc = qq << 5;            // 0,32,64,96 (wave-uniform)
            float acc[32];
#pragma unroll
            for (int jj = 0; jj < 32; ++jj) acc[jj] = pb3[jc + jj];
            for (int k = 0; k < 64; ++k) {
                const float xk = x2T[k][p];
#pragma unroll
                for (int jj = 0; jj < 32; ++jj)
                    acc[jj] = fmaf(xk, pw3[k * 128 + jc + jj], acc[jj]);
            }
#pragma unroll
            for (int jj = 0; jj < 32; ++jj)
                x3T[jc + jj][p] = fmaxf(acc[jj], 0.f);
        }
        __syncthreads();

        // ---- 2: layer 4 (128 -> 300) + running segmented max ----
        if (p2act) {
            int as = gs - t0; if (as < 0) as = 0;
            int ae = ge - t0; if (ae > np) ae = np;
            for (int jb = (as & ~(PB - 1)); jb < ae; jb += PB) {
                float acc0[PB], acc1[PB];
#pragma unroll
                for (int i = 0; i < PB; ++i) { acc0[i] = 0.f; acc1[i] = 0.f; }
                for (int k = 0; k < 128; ++k) {
                    const float wa = pw4[k * D_OUT + cc];
                    const float wb = pw4[k * D_OUT + cc + 150];
#pragma unroll
                    for (int u = 0; u < PB / 4; ++u) {
                        const float4 xv = *(const float4*)&x3T[k][jb + 4 * u];
                        acc0[4*u+0] = fmaf(xv.x, wa, acc0[4*u+0]);
                        acc0[4*u+1] = fmaf(xv.y, wa, acc0[4*u+1]);
                        acc0[4*u+2] = fmaf(xv.z, wa, acc0[4*u+2]);
                        acc0[4*u+3] = fmaf(xv.w, wa, acc0[4*u+3]);
                        acc1[4*u+0] = fmaf(xv.x, wb, acc1[4*u+0]);
                        acc1[4*u+1] = fmaf(xv.y, wb, acc1[4*u+1]);
                        acc1[4*u+2] = fmaf(xv.z, wb, acc1[4*u+2]);
                        acc1[4*u+3] = fmaf(xv.w, wb, acc1[4*u+3]);
                    }
                }
#pragma unroll
                for (int i = 0; i < PB; ++i) {
                    const int s = jb + i;
                    if (s >= as && s < ae) {
                        vmax0 = fmaxf(vmax0, acc0[i]);
                        vmax1 = fmaxf(vmax1, acc1[i]);
                    }
                }
            }
        }
        __syncthreads();
    }

    if (p2act) {
        const int g = gA + gsel;
        // empty segment: vmax=-inf -> relu gives 0 (matches max(segmax,0))
        agg[(size_t)g * D_OUT + cc]       = fmaxf(vmax0 + pb4[cc], 0.f);
        agg[(size_t)g * D_OUT + cc + 150] = fmaxf(vmax1 + pb4[cc + 150], 0.f);
    }
}

// ---------------------------------------------------------------------------
// Output MLP (unchanged; in-place safe: block reads its 32 rows before write).
// ---------------------------------------------------------------------------
__global__ __launch_bounds__(320, 2) void out_mlp(
    const float* __restrict__ agg,
    const float* __restrict__ ow1, const float* __restrict__ ob1,
    const float* __restrict__ ow2, const float* __restrict__ ob2,
    float* __restrict__ y)
{
    __shared__ float A[TR * D_OUT];
    __shared__ float H[TR * D_OUT];
    const int t = threadIdx.x;
    const long rb = (long)blockIdx.x * TR;

    for (int l = t; l < TR * D_OUT; l += 320) A[l] = agg[rb * D_OUT + l];
    __syncthreads();

    if (t < D_OUT) {
        float acc[TR];
#pragma unroll
        for (int r = 0; r < TR; ++r) acc[r] = ob1[t];
        for (int k = 0; k < D_OUT; k += 4) {
            const float w0 = ow1[(k + 0) * D_OUT + t];
            const float w1 = ow1[(k + 1) * D_OUT + t];
            const float w2 = ow1[(k + 2) * D_OUT + t];
            const float w3 = ow1[(k + 3) * D_OUT + t];
#pragma unroll
            for (int r = 0; r < TR; ++r) {
                const float4 a4 = *reinterpret_cast<const float4*>(&A[r * D_OUT + k]);
                acc[r] = fmaf(a4.x, w0, acc[r]);
                acc[r] = fmaf(a4.y, w1, acc[r]);
                acc[r] = fmaf(a4.z, w2, acc[r]);
                acc[r] = fmaf(a4.w, w3, acc[r]);
            }
        }
#pragma unroll
        for (int r = 0; r < TR; ++r) H[r * D_OUT + t] = fmaxf(acc[r], 0.f);
    }
    __syncthreads();

    if (t < D_OUT) {
        float acc[TR];
#pragma unroll
        for (int r = 0; r < TR; ++r) acc[r] = ob2[t];
        for (int k = 0; k < D_OUT; k += 4) {
            const float w0 = ow2[(k + 0) * D_OUT + t];
            const float w1 = ow2[(k + 1) * D_OUT + t];
            const float w2 = ow2[(k + 2) * D_OUT + t];
            const float w3 = ow2[(k + 3) * D_OUT + t];
#pragma unroll
            for (int r = 0; r < TR; ++r) {
                const float4 h4 = *reinterpret_cast<const float4*>(&H[r * D_OUT + k]);
                acc[r] = fmaf(h4.x, w0, acc[r]);
                acc[r] = fmaf(h4.y, w1, acc[r]);
                acc[r] = fmaf(h4.z, w2, acc[r]);
                acc[r] = fmaf(h4.w, w3, acc[r]);
            }
        }
#pragma unroll
        for (int r = 0; r < TR; ++r) y[(rb + r) * D_OUT + t] = fmaxf(acc[r], 0.f);
    }
}

extern "C" void kernel_launch(void* const* d_in, const int* in_sizes, int n_in,
                              void* d_out, int out_size, void* d_ws, size_t ws_size,
                              hipStream_t stream) {
    const float* features    = (const float*)d_in[0];
    const float* coords      = (const float*)d_in[1];
    const int*   keypoints   = (const int*)d_in[2];
    const int*   set_indices = (const int*)d_in[3];
    const float* pw1 = (const float*)d_in[4];
    const float* pb1 = (const float*)d_in[5];
    const float* pw2 = (const float*)d_in[6];
    const float* pb2 = (const float*)d_in[7];
    const float* pw3 = (const float*)d_in[8];
    const float* pb3 = (const float*)d_in[9];
    const float* pw4 = (const float*)d_in[10];
    const float* pb4 = (const float*)d_in[11];
    const float* ow1 = (const float*)d_in[12];
    const float* ob1 = (const float*)d_in[13];
    const float* ow2 = (const float*)d_in[14];
    const float* ob2 = (const float*)d_in[15];

    const int* si_set = set_indices + N_PAIRS;

    // ws layout: CSR only (~2.2 MB)
    char* w = (char*)d_ws;
    int* cnt      = (int*)w;  w += 65536;
    int* off      = (int*)w;  w += 65792;   // 16385 ints, padded
    int* cursor   = (int*)w;  w += 65536;
    int* pairlist = (int*)w;

    float* agg = (float*)d_out;   // out_mlp runs in-place (read-before-write)
    float* y   = (float*)d_out;

    hipMemsetAsync(cnt, 0, 65536, stream);
    k_count<<<N_PAIRS / 256, 256, 0, stream>>>(si_set, cnt);
    k_scan<<<1, 256, 0, stream>>>(cnt, off, cursor);
    k_fill<<<N_PAIRS / 256, 256, 0, stream>>>(si_set, cursor, pairlist);

    fused_point<<<N_KEYPOINTS / 2, 320, 0, stream>>>(
        features, coords, keypoints, set_indices, pairlist, off,
        pw1, pb1, pw2, pb2, pw3, pb3, pw4, pb4, agg);

    out_mlp<<<N_KEYPOINTS / TR, 320, 0, stream>>>(agg, ow1, ob1, ow2, ob2, y);
}